// Round 2
// baseline (4753.780 us; speedup 1.0000x reference)
//
#include <hip/hip_runtime.h>
#include <hip/hip_fp16.h>

typedef unsigned short u16;
typedef _Float16 half8 __attribute__((ext_vector_type(8)));
typedef float floatx4 __attribute__((ext_vector_type(4)));

#define NB 32
#define NS 256
#define NSE 1024
#define ND 512
#define NV 8000
#define NL 4
#define NH 8
#define NDK 64
#define BN_EPS 1e-3f

// ---------------- fp32 -> fp16 cast (8 elems/thread) ----------------
__global__ __launch_bounds__(256) void k_cast(const float* __restrict__ in, _Float16* __restrict__ out) {
    size_t i = ((size_t)blockIdx.x * 256 + threadIdx.x) * 8;
    float4 a = *(const float4*)(in + i);
    float4 b = *(const float4*)(in + i + 4);
    half8 o;
    o[0] = (_Float16)a.x; o[1] = (_Float16)a.y; o[2] = (_Float16)a.z; o[3] = (_Float16)a.w;
    o[4] = (_Float16)b.x; o[5] = (_Float16)b.y; o[6] = (_Float16)b.z; o[7] = (_Float16)b.w;
    *(half8*)(out + i) = o;
}

// ---------------- embedding + positional (fp32 in, fp16 out) ----------------
__global__ __launch_bounds__(256) void k_embed(const int* __restrict__ seq,
                                               const float* __restrict__ emb,
                                               const float* __restrict__ pos,
                                               _Float16* __restrict__ x) {
    size_t i = ((size_t)blockIdx.x * 256 + threadIdx.x) * 8;
    int tok = (int)(i / ND);                                 // b*NS + s
    int d = (int)(i % ND);
    int s = tok % NS;
    int t = seq[tok];
    const float* ep = emb + (size_t)t * ND + d;
    const float* pp = pos + (size_t)s * ND + d;
    half8 o;
    for (int j = 0; j < 8; j++) o[j] = (_Float16)(ep[j] + pp[j]);
    *(half8*)(x + i) = o;
}

// ---------------- residual + BatchNorm (inference); params fp32 ----------------
__global__ __launch_bounds__(256) void k_bnres(const _Float16* __restrict__ xin, const _Float16* __restrict__ a,
                                               const float* __restrict__ gamma, const float* __restrict__ beta,
                                               const float* __restrict__ mean, const float* __restrict__ var,
                                               _Float16* __restrict__ xout) {
    size_t i = ((size_t)blockIdx.x * 256 + threadIdx.x) * 8;
    int d = (int)(i % ND);
    half8 xv = *(const half8*)(xin + i);
    half8 av = *(const half8*)(a + i);
    half8 o;
    for (int j = 0; j < 8; j++) {
        float v = (float)xv[j] + (float)av[j];
        float r = rsqrtf(var[d + j] + BN_EPS);
        o[j] = (_Float16)(((v - mean[d + j]) * r) * gamma[d + j] + beta[d + j]);
    }
    *(half8*)(xout + i) = o;
}

// ------------- weight transpose + cast: in fp32 [R][C] -> out fp16 [C][R] -------------
__global__ void k_transpose_w(const float* __restrict__ in, _Float16* __restrict__ out, int R, int C) {
    __shared__ float tile[32][33];
    int b = blockIdx.z;
    int c0 = blockIdx.x * 32, r0 = blockIdx.y * 32;
    const float* pin = in + (size_t)b * R * C;
    _Float16* pout = out + (size_t)b * R * C;
    int tx = threadIdx.x, ty = threadIdx.y;                  // block (32,8)
    for (int j = 0; j < 32; j += 8)
        tile[ty + j][tx] = pin[(size_t)(r0 + ty + j) * C + c0 + tx];
    __syncthreads();
    for (int j = 0; j < 32; j += 8)
        pout[(size_t)(c0 + ty + j) * R + r0 + tx] = (_Float16)tile[tx][ty + j];
}

// ---------------- fp16 MFMA GEMM: C[M,N] = A[M,K] @ Bt[N,K]^T + bias ----------
// 128x128 tile, 256 thr = 4 waves (2x2), wave = 64x64 via 4x4 mfma_f32_16x16x32_f16.
// outmode: 0 = fp16 row-major, 1 = fp16 per-batch transposed [b][col][s] (Sb rows/batch),
//          2 = fp32 row-major (final logits). relu applied if flag set.
#define BM 128
#define BNT 128
#define BK 64
__global__ __launch_bounds__(256) void k_gemm(const _Float16* __restrict__ A, const _Float16* __restrict__ Bt,
                                              const float* __restrict__ bias, void* __restrict__ Cout,
                                              int M, int N, int K, int relu, int outmode, int Sb) {
    __shared__ _Float16 As[BM][BK + 8];
    __shared__ _Float16 Bs[BNT][BK + 8];
    int tid = threadIdx.x;
    int m0 = blockIdx.y * BM;
    int n0 = blockIdx.x * BNT;
    int wid = tid >> 6;
    int lane = tid & 63;
    int quad = lane >> 4, r = lane & 15;
    int wm = (wid >> 1) * 64, wn = (wid & 1) * 64;

    floatx4 zf = {0.f, 0.f, 0.f, 0.f};
    floatx4 acc[4][4];
    for (int i = 0; i < 4; i++) for (int j = 0; j < 4; j++) acc[i][j] = zf;

    int arow = tid >> 3;            // 0..31
    int acol = (tid & 7) * 8;       // 0..56

    for (int k0 = 0; k0 < K; k0 += BK) {
        __syncthreads();
        for (int i = 0; i < 4; i++) {
            int row = arow + i * 32;
            *(half8*)&As[row][acol] = *(const half8*)(A + (size_t)(m0 + row) * K + k0 + acol);
        }
        for (int i = 0; i < 4; i++) {
            int row = arow + i * 32;
            int gn = n0 + row;
            half8 v;
            if (gn < N) v = *(const half8*)(Bt + (size_t)gn * K + k0 + acol);
            else for (int j = 0; j < 8; j++) v[j] = (_Float16)0.0f;
            *(half8*)&Bs[row][acol] = v;
        }
        __syncthreads();
        for (int ks = 0; ks < BK; ks += 32) {
            half8 af[4], bg[4];
            for (int i = 0; i < 4; i++) af[i] = *(const half8*)&As[wm + i * 16 + r][ks + quad * 8];
            for (int j = 0; j < 4; j++) bg[j] = *(const half8*)&Bs[wn + j * 16 + r][ks + quad * 8];
            for (int i = 0; i < 4; i++)
                for (int j = 0; j < 4; j++)
                    acc[i][j] = __builtin_amdgcn_mfma_f32_16x16x32_f16(af[i], bg[j], acc[i][j], 0, 0, 0);
        }
    }
    for (int j = 0; j < 4; j++) {
        int col = n0 + wn + j * 16 + r;
        if (col >= N) continue;
        float bv = bias[col];
        for (int i = 0; i < 4; i++) {
            int rowbase = m0 + wm + i * 16 + quad * 4;      // C/D: row = quad*4+g, col = lane&15
            for (int g = 0; g < 4; g++) {
                float v = acc[i][j][g] + bv;
                if (relu) v = fmaxf(v, 0.0f);
                int row = rowbase + g;
                if (outmode == 0) {
                    ((_Float16*)Cout)[(size_t)row * N + col] = (_Float16)v;
                } else if (outmode == 1) {
                    int b = row / Sb, s = row - b * Sb;
                    ((_Float16*)Cout)[(size_t)b * N * Sb + (size_t)col * Sb + s] = (_Float16)v;
                } else {
                    ((float*)Cout)[(size_t)row * N + col] = v;
                }
            }
        }
    }
}

// ---------------- fused flash attention (fp16 in/out, fp32 softmax) ----------------
// grid (S/64, H, B), 256 thr = 4 waves; wave w owns 16 q-rows. dk=64.
// Q,K: [B,*,D] row-major. Vt: [B, D, Sk].
__global__ __launch_bounds__(256) void k_attn(const _Float16* __restrict__ Q, const _Float16* __restrict__ Kb,
                                              const _Float16* __restrict__ Vt, _Float16* __restrict__ O,
                                              int Sk, int causal) {
    __shared__ _Float16 Plds[4][16][72];
    int qt = blockIdx.x, h = blockIdx.y, b = blockIdx.z;
    int tid = threadIdx.x;
    int w = tid >> 6, lane = tid & 63, quad = lane >> 4, r = lane & 15;
    int qbase = qt * 64 + w * 16;

    floatx4 zf = {0.f, 0.f, 0.f, 0.f};
    // Q A-frags (A[m=lane&15][k=quad*8+j]), dk=64 -> two k-steps
    half8 aq[2];
    const _Float16* qptr = Q + (size_t)(b * NS + qbase + r) * ND + h * NDK;
    aq[0] = *(const half8*)(qptr + quad * 8);
    aq[1] = *(const half8*)(qptr + 32 + quad * 8);

    floatx4 Of[4];
    for (int j = 0; j < 4; j++) Of[j] = zf;
    float mrow[4], lrow[4];
    for (int g = 0; g < 4; g++) { mrow[g] = -1e30f; lrow[g] = 0.0f; }

    int ntiles = causal ? (qt + 1) : (Sk >> 6);

    for (int kt = 0; kt < ntiles; kt++) {
        floatx4 sc[4];
        for (int j = 0; j < 4; j++) sc[j] = zf;
        for (int t = 0; t < 2; t++) {
            for (int j = 0; j < 4; j++) {
                const _Float16* kptr = Kb + (size_t)(b * Sk + kt * 64 + j * 16 + r) * ND + h * NDK + t * 32 + quad * 8;
                half8 bk = *(const half8*)kptr;
                sc[j] = __builtin_amdgcn_mfma_f32_16x16x32_f16(aq[t], bk, sc[j], 0, 0, 0);
            }
        }
        // scale + causal mask; C/D: row = quad*4+g (q), col = lane&15 (key)
        float s[4][4], tmax[4];
        for (int g = 0; g < 4; g++) tmax[g] = -1e30f;
        for (int j = 0; j < 4; j++) {
            int key = kt * 64 + j * 16 + r;
            for (int g = 0; g < 4; g++) {
                float v = sc[j][g] * 0.125f;                 // 1/sqrt(64)
                int qi = qbase + quad * 4 + g;
                if (causal && key >= qi) v = -1e30f;         // strict: attend only key < q
                s[j][g] = v;
                tmax[g] = fmaxf(tmax[g], v);
            }
        }
        for (int off = 1; off < 16; off <<= 1)
            for (int g = 0; g < 4; g++)
                tmax[g] = fmaxf(tmax[g], __shfl_xor(tmax[g], off, 64));
        float alpha[4], psum[4];
        for (int g = 0; g < 4; g++) {
            float mnew = fmaxf(mrow[g], tmax[g]);
            alpha[g] = (mnew <= -1e29f) ? 1.0f : __expf(mrow[g] - mnew);
            mrow[g] = mnew;
            psum[g] = 0.0f;
        }
        for (int j = 0; j < 4; j++) {
            for (int g = 0; g < 4; g++) {
                float p = (s[j][g] <= -1e29f) ? 0.0f : __expf(s[j][g] - mrow[g]);
                psum[g] += p;
                Plds[w][quad * 4 + g][j * 16 + r] = (_Float16)p;
            }
        }
        for (int off = 1; off < 16; off <<= 1)
            for (int g = 0; g < 4; g++)
                psum[g] += __shfl_xor(psum[g], off, 64);
        for (int g = 0; g < 4; g++) lrow[g] = lrow[g] * alpha[g] + psum[g];
        for (int j = 0; j < 4; j++)
            for (int g = 0; g < 4; g++)
                Of[j][g] *= alpha[g];
        __syncthreads();   // order P writes before frag reads (uniform trip count per block)
        for (int t = 0; t < 2; t++) {
            half8 ap = *(const half8*)&Plds[w][r][t * 32 + quad * 8];
            for (int j = 0; j < 4; j++) {
                const _Float16* vptr = Vt + (size_t)((b * NH + h) * NDK + j * 16 + r) * Sk + kt * 64 + t * 32 + quad * 8;
                half8 bv = *(const half8*)vptr;
                Of[j] = __builtin_amdgcn_mfma_f32_16x16x32_f16(ap, bv, Of[j], 0, 0, 0);
            }
        }
        __syncthreads();
    }
    for (int j = 0; j < 4; j++) {
        for (int g = 0; g < 4; g++) {
            int row = qbase + quad * 4 + g;
            float inv = (lrow[g] > 0.f) ? 1.0f / lrow[g] : 0.0f;   // fully-masked row -> exact 0
            O[(size_t)(b * NS + row) * ND + h * NDK + j * 16 + r] = (_Float16)(Of[j][g] * inv);
        }
    }
}

extern "C" void kernel_launch(void* const* d_in, const int* in_sizes, int n_in,
                              void* d_out, int out_size, void* d_ws, size_t ws_size,
                              hipStream_t stream) {
    const int*   seq  = (const int*)d_in[0];
    const float* enc  = (const float*)d_in[1];
    const float* pos  = (const float*)d_in[2];
    const float* emb  = (const float*)d_in[3];
    const float* Wout = (const float*)d_in[4];
    const float* bout = (const float*)d_in[5];
    const float* W1   = (const float*)d_in[6];
    const float* b1   = (const float*)d_in[7];
    const float* W2   = (const float*)d_in[8];
    const float* b2   = (const float*)d_in[9];
    const float* Wq_bot = (const float*)d_in[10];
    const float* Wk_bot = (const float*)d_in[11];
    const float* Wv_bot = (const float*)d_in[12];
    const float* Wo_bot = (const float*)d_in[13];
    const float* bq_bot = (const float*)d_in[14];
    const float* bk_bot = (const float*)d_in[15];
    const float* bv_bot = (const float*)d_in[16];
    const float* bo_bot = (const float*)d_in[17];
    const float* Wq_mid = (const float*)d_in[18];
    const float* Wk_mid = (const float*)d_in[19];
    const float* Wv_mid = (const float*)d_in[20];
    const float* Wo_mid = (const float*)d_in[21];
    const float* bq_mid = (const float*)d_in[22];
    const float* bk_mid = (const float*)d_in[23];
    const float* bv_mid = (const float*)d_in[24];
    const float* bo_mid = (const float*)d_in[25];
    const float* gam[3] = {(const float*)d_in[26], (const float*)d_in[30], (const float*)d_in[34]};
    const float* bet[3] = {(const float*)d_in[27], (const float*)d_in[31], (const float*)d_in[35]};
    const float* mea[3] = {(const float*)d_in[28], (const float*)d_in[32], (const float*)d_in[36]};
    const float* vr [3] = {(const float*)d_in[29], (const float*)d_in[33], (const float*)d_in[37]};

    char* wp = (char*)d_ws;
    auto alloc = [&](size_t elems) -> _Float16* {
        _Float16* p = (_Float16*)wp;
        wp += ((elems * 2 + 255) / 256) * 256;
        return p;
    };
    const size_t DD = (size_t)ND * ND;
    _Float16* WqTb = alloc(NL * DD);
    _Float16* WkTb = alloc(NL * DD);
    _Float16* WvTb = alloc(NL * DD);
    _Float16* WoTb = alloc(NL * DD);
    _Float16* WqTm = alloc(NL * DD);
    _Float16* WkTm = alloc(NL * DD);
    _Float16* WvTm = alloc(NL * DD);
    _Float16* WoTm = alloc(NL * DD);
    _Float16* W1T  = alloc(NL * DD);
    _Float16* W2T  = alloc(NL * DD);
    _Float16* WoutT = alloc((size_t)NV * ND);
    const size_t XSZ = (size_t)NB * NS * ND;    // 4.19M elems
    _Float16* x   = alloc(XSZ);
    _Float16* qb  = alloc(XSZ);
    _Float16* kb  = alloc(XSZ);
    _Float16* vts = alloc(XSZ);                 // V^T self  [B,D,S]
    _Float16* ao  = alloc(XSZ);
    const size_t ESZ = (size_t)NB * NSE * ND;   // 16.78M elems
    _Float16* ench  = alloc(ESZ);               // fp16 encoder
    _Float16* kenc  = alloc(ESZ);
    _Float16* vtenc = alloc(ESZ);               // V^T cross [B,D,SE]

    dim3 tb(32, 8);
    // weight pre-transposes + fp16 cast: W[K][N] -> Wt[N][K]
    k_transpose_w<<<dim3(ND / 32, ND / 32, NL), tb, 0, stream>>>(Wq_bot, WqTb, ND, ND);
    k_transpose_w<<<dim3(ND / 32, ND / 32, NL), tb, 0, stream>>>(Wk_bot, WkTb, ND, ND);
    k_transpose_w<<<dim3(ND / 32, ND / 32, NL), tb, 0, stream>>>(Wv_bot, WvTb, ND, ND);
    k_transpose_w<<<dim3(ND / 32, ND / 32, NL), tb, 0, stream>>>(Wo_bot, WoTb, ND, ND);
    k_transpose_w<<<dim3(ND / 32, ND / 32, NL), tb, 0, stream>>>(Wq_mid, WqTm, ND, ND);
    k_transpose_w<<<dim3(ND / 32, ND / 32, NL), tb, 0, stream>>>(Wk_mid, WkTm, ND, ND);
    k_transpose_w<<<dim3(ND / 32, ND / 32, NL), tb, 0, stream>>>(Wv_mid, WvTm, ND, ND);
    k_transpose_w<<<dim3(ND / 32, ND / 32, NL), tb, 0, stream>>>(Wo_mid, WoTm, ND, ND);
    k_transpose_w<<<dim3(ND / 32, ND / 32, NL), tb, 0, stream>>>(W1, W1T, ND, ND);
    k_transpose_w<<<dim3(ND / 32, ND / 32, NL), tb, 0, stream>>>(W2, W2T, ND, ND);
    k_transpose_w<<<dim3(NV / 32, ND / 32, 1), tb, 0, stream>>>(Wout, WoutT, ND, NV);
    k_cast<<<dim3((int)(ESZ / 8 / 256)), 256, 0, stream>>>(enc, ench);

    auto gemm = [&](const _Float16* A, const _Float16* Bt, const float* bias, void* C,
                    int M, int N, int relu, int outmode, int Sb) {
        k_gemm<<<dim3((N + 127) / 128, M / 128), 256, 0, stream>>>(A, Bt, bias, C, M, N, ND, relu, outmode, Sb);
    };

    k_embed<<<dim3((int)(XSZ / 8 / 256)), 256, 0, stream>>>(seq, emb, pos, x);

    const int M = NB * NS;        // 8192
    const int ME = NB * NSE;      // 32768
    for (int l = 0; l < NL; l++) {
        size_t wofs = (size_t)l * DD;
        size_t bofs = (size_t)l * ND;
        // --- causal self-attention ---
        gemm(x, WqTb + wofs, bq_bot + bofs, qb, M, ND, 0, 0, 0);
        gemm(x, WkTb + wofs, bk_bot + bofs, kb, M, ND, 0, 0, 0);
        gemm(x, WvTb + wofs, bv_bot + bofs, vts, M, ND, 0, 1, NS);   // store V^T per batch
        k_attn<<<dim3(NS / 64, NH, NB), 256, 0, stream>>>(qb, kb, vts, ao, NS, 1);
        gemm(ao, WoTb + wofs, bo_bot + bofs, kb, M, ND, 0, 0, 0);    // reuse kb as attn-proj out
        k_bnres<<<dim3((int)(XSZ / 8 / 256)), 256, 0, stream>>>(x, kb, gam[0] + bofs, bet[0] + bofs, mea[0] + bofs, vr[0] + bofs, x);
        // --- cross-attention ---
        gemm(x, WqTm + wofs, bq_mid + bofs, qb, M, ND, 0, 0, 0);
        gemm(ench, WkTm + wofs, bk_mid + bofs, kenc, ME, ND, 0, 0, 0);
        gemm(ench, WvTm + wofs, bv_mid + bofs, vtenc, ME, ND, 0, 1, NSE);
        k_attn<<<dim3(NS / 64, NH, NB), 256, 0, stream>>>(qb, kenc, vtenc, ao, NSE, 0);
        gemm(ao, WoTm + wofs, bo_mid + bofs, kb, M, ND, 0, 0, 0);
        k_bnres<<<dim3((int)(XSZ / 8 / 256)), 256, 0, stream>>>(x, kb, gam[1] + bofs, bet[1] + bofs, mea[1] + bofs, vr[1] + bofs, x);
        // --- FFN ---
        gemm(x, W1T + wofs, b1 + bofs, qb, M, ND, 1, 0, 0);
        gemm(qb, W2T + wofs, b2 + bofs, kb, M, ND, 0, 0, 0);
        k_bnres<<<dim3((int)(XSZ / 8 / 256)), 256, 0, stream>>>(x, kb, gam[2] + bofs, bet[2] + bofs, mea[2] + bofs, vr[2] + bofs, x);
    }
    // --- final vocab projection, fp32 straight to d_out ---
    gemm(x, WoutT, bout, (float*)d_out, M, NV, 0, 2, 0);
}